// Round 3
// baseline (1233.699 us; speedup 1.0000x reference)
//
#include <hip/hip_runtime.h>
#include <math.h>

#define N 8192
#define NF4 2048  // N/4 float4s per row

// Sinkhorn via potentials: u_i = LSE_j(s_ij - v_j); v'_j = LSE_i(s_ij - u_i).
// Fused strip pass (round-1 two-barrier schedule, 512-thread blocks):
// block owns R rows; computes u for its rows AND the strip's column partial
// sums pt[strip][j] = sum_i exp(s_ij - v_j - u_i) from ONE read of s
// (v'_j = v_j + log(sum over strips); terms <= 1, no online max needed).
// 16 elems/thread, in-place buf transform, triple-buffered row prefetch:
// state ~80 VGPR -> 4 waves/SIMD (16 waves/CU) under __launch_bounds__(512,4).

__device__ __forceinline__ float wave_max(float m) {
#pragma unroll
  for (int off = 32; off > 0; off >>= 1) m = fmaxf(m, __shfl_xor(m, off, 64));
  return m;
}
__device__ __forceinline__ float wave_sum(float s) {
#pragma unroll
  for (int off = 32; off > 0; off >>= 1) s += __shfl_xor(s, off, 64);
  return s;
}

template <int R>
__global__ __launch_bounds__(512, 4) void fused_pass(
    const float* __restrict__ s, const float* __restrict__ v,
    float* __restrict__ u, float* __restrict__ pt, int use_v) {
  const int t = threadIdx.x;
  const int wid = t >> 6, lane = t & 63;
  const int row0 = blockIdx.x * R;
  __shared__ float red[16];  // [0..7] wave max, [8..15] wave sum

  float4 vv[4];
  if (use_v) {
    const float4* v4 = (const float4*)v;
#pragma unroll
    for (int k = 0; k < 4; ++k) vv[k] = v4[t + k * 512];
  } else {
#pragma unroll
    for (int k = 0; k < 4; ++k) vv[k] = make_float4(0.f, 0.f, 0.f, 0.f);
  }

  float4 acc[4];
#pragma unroll
  for (int k = 0; k < 4; ++k) acc[k] = make_float4(0.f, 0.f, 0.f, 0.f);

  const float4* s4 = (const float4*)s + (size_t)row0 * NF4;
  float4 bufs[3][4];  // triple buffer; full unroll keeps indices static

#pragma unroll
  for (int k = 0; k < 4; ++k) bufs[0][k] = s4[t + k * 512];
#pragma unroll
  for (int k = 0; k < 4; ++k) bufs[1][k] = s4[NF4 + t + k * 512];

#pragma unroll
  for (int r = 0; r < R; ++r) {
    float4(&cur)[4] = bufs[r % 3];
    if (r + 2 < R) {  // depth-2 prefetch into the buffer freed at row r-1
      const float4* p = s4 + (size_t)(r + 2) * NF4;
      float4(&nb)[4] = bufs[(r + 2) % 3];
#pragma unroll
      for (int k = 0; k < 4; ++k) nb[k] = p[t + k * 512];
    }
    // P1: subtract v, wave max
    float m0 = -INFINITY, m1 = -INFINITY, m2 = -INFINITY, m3 = -INFINITY;
#pragma unroll
    for (int k = 0; k < 4; ++k) {
      cur[k].x -= vv[k].x; cur[k].y -= vv[k].y;
      cur[k].z -= vv[k].z; cur[k].w -= vv[k].w;
      m0 = fmaxf(m0, cur[k].x); m1 = fmaxf(m1, cur[k].y);
      m2 = fmaxf(m2, cur[k].z); m3 = fmaxf(m3, cur[k].w);
    }
    const float m = wave_max(fmaxf(fmaxf(m0, m1), fmaxf(m2, m3)));
    if (lane == 0) red[wid] = m;
    __syncthreads();
    float bm = red[0];
#pragma unroll
    for (int w = 1; w < 8; ++w) bm = fmaxf(bm, red[w]);
    // P2: exp in place, wave sum
    float s0 = 0.f, s1 = 0.f, s2 = 0.f, s3 = 0.f;
#pragma unroll
    for (int k = 0; k < 4; ++k) {
      cur[k].x = __expf(cur[k].x - bm); cur[k].y = __expf(cur[k].y - bm);
      cur[k].z = __expf(cur[k].z - bm); cur[k].w = __expf(cur[k].w - bm);
      s0 += cur[k].x; s1 += cur[k].y; s2 += cur[k].z; s3 += cur[k].w;
    }
    const float ss = wave_sum((s0 + s1) + (s2 + s3));
    if (lane == 0) red[8 + wid] = ss;
    __syncthreads();
    float tot = red[8];
#pragma unroll
    for (int w = 1; w < 8; ++w) tot += red[8 + w];
    if (t == 0) u[row0 + r] = bm + __logf(tot);
    const float inv = 1.0f / tot;
    // P3: accumulate column partials
#pragma unroll
    for (int k = 0; k < 4; ++k) {
      acc[k].x = fmaf(cur[k].x, inv, acc[k].x);
      acc[k].y = fmaf(cur[k].y, inv, acc[k].y);
      acc[k].z = fmaf(cur[k].z, inv, acc[k].z);
      acc[k].w = fmaf(cur[k].w, inv, acc[k].w);
    }
  }

  float4* p4 = (float4*)(pt + (size_t)blockIdx.x * N);
#pragma unroll
  for (int k = 0; k < 4; ++k) p4[t + k * 512] = acc[k];
}

// Stage 1: group-sum strips. ps[g][j] = sum over per_group strips of pt.
__global__ __launch_bounds__(256) void combine1(const float* __restrict__ pt,
                                                float* __restrict__ ps,
                                                int per_group) {
  const int j = blockIdx.x * 256 + threadIdx.x;
  const int g = blockIdx.y;
  const float* p = pt + (size_t)g * per_group * N + j;
  float acc = 0.f;
  for (int c = 0; c < per_group; ++c) acc += p[(size_t)c * N];
  ps[(size_t)g * N + j] = acc;
}

// Stage 2: v'_j = (add_old ? v_j : 0) + log(sum_g ps[g][j])
__global__ __launch_bounds__(256) void combine2(const float* __restrict__ ps,
                                                float* __restrict__ v,
                                                int ngroups, int add_old) {
  const int j = blockIdx.x * 256 + threadIdx.x;
  float T = 0.f;
  for (int g = 0; g < ngroups; ++g) T += ps[(size_t)g * N + j];
  const float lv = __logf(T);
  v[j] = add_old ? v[j] + lv : lv;
}

// out = exp(s - u_i - v_j)
__global__ __launch_bounds__(256) void finalize_k(const float* __restrict__ s,
                                                  const float* __restrict__ u,
                                                  const float* __restrict__ v,
                                                  float* __restrict__ out) {
  const size_t idx = (size_t)blockIdx.x * 256 + threadIdx.x;  // float4 index
  const int row = (int)(idx >> 11);
  const int c4 = (int)(idx & 2047);
  const float4 sv = ((const float4*)s)[idx];
  const float4 vv = ((const float4*)v)[c4];
  const float ur = u[row];
  float4 o;
  o.x = __expf(sv.x - ur - vv.x);
  o.y = __expf(sv.y - ur - vv.y);
  o.z = __expf(sv.z - ur - vv.z);
  o.w = __expf(sv.w - ur - vv.w);
  ((float4*)out)[idx] = o;
}

extern "C" void kernel_launch(void* const* d_in, const int* in_sizes, int n_in,
                              void* d_out, int out_size, void* d_ws, size_t ws_size,
                              hipStream_t stream) {
  const float* s = (const float*)d_in[0];
  float* out = (float*)d_out;
  float* ws = (float*)d_ws;

  // workspace: u[N] | v[N] | ps[8*N] | pt[nstrips*N]
  const size_t avail = ws_size / sizeof(float);
  int nstrips = 512;
  while (nstrips > 128 && (size_t)(10 + nstrips) * N > avail) nstrips >>= 1;
  float* u = ws;
  float* v = ws + N;
  float* ps = ws + 2 * N;
  float* pt = ws + 10 * N;
  const int G = 8;
  const int per_group = nstrips / G;

  for (int p = 0; p < 5; ++p) {
    const int use_v = p > 0 ? 1 : 0;
    switch (nstrips) {
      case 512:
        fused_pass<16><<<512, 512, 0, stream>>>(s, v, u, pt, use_v);
        break;
      case 256:
        fused_pass<32><<<256, 512, 0, stream>>>(s, v, u, pt, use_v);
        break;
      default:
        fused_pass<64><<<128, 512, 0, stream>>>(s, v, u, pt, use_v);
        break;
    }
    combine1<<<dim3(N / 256, G), 256, 0, stream>>>(pt, ps, per_group);
    combine2<<<N / 256, 256, 0, stream>>>(ps, v, G, p > 0 ? 1 : 0);
  }
  finalize_k<<<(N / 256) * NF4, 256, 0, stream>>>(s, u, v, out);
}

// Round 4
// 799.511 us; speedup vs baseline: 1.5431x; 1.5431x over previous
//
#include <hip/hip_runtime.h>
#include <math.h>

#define N 8192
#define NF4 2048  // N/4 float4s per row

// Sinkhorn via potentials: u_i = LSE_j(s_ij - v_j); v'_j = LSE_i(s_ij - u_i).
// Fused strip pass: block owns R rows; computes u for its rows AND the strip's
// column partial sums pt[strip][j] = sum_i exp(s_ij - v_j - u_i) from ONE read
// of s (v'_j = v_j + log(sum over strips); terms <= 1, no online max needed).
//
// Occupancy-first config (round-3 post-mortem: 211 MB/dispatch scratch spill
// at forced 64 VGPR): 512 thr/block, 16 elems/thread, in-place transform,
// v in LDS (each thread reads only the slots it wrote -> no barrier), NO
// register prefetch. State ~55 VGPR -> fits the 64-VGPR bucket ->
// 8 waves/SIMD = 32 waves/CU (4 blocks/CU, 129 KB LDS). TLP, not ILP,
// covers HBM latency.

__device__ __forceinline__ float wave_max(float m) {
#pragma unroll
  for (int off = 32; off > 0; off >>= 1) m = fmaxf(m, __shfl_xor(m, off, 64));
  return m;
}
__device__ __forceinline__ float wave_sum(float s) {
#pragma unroll
  for (int off = 32; off > 0; off >>= 1) s += __shfl_xor(s, off, 64);
  return s;
}

template <int R>
__global__ __launch_bounds__(512, 8) void fused_pass(
    const float* __restrict__ s, const float* __restrict__ v,
    float* __restrict__ u, float* __restrict__ pt, int use_v) {
  const int t = threadIdx.x;
  const int wid = t >> 6, lane = t & 63;
  const int row0 = blockIdx.x * R;
  __shared__ float4 vsh[NF4];  // 32 KB
  __shared__ float red[16];    // [0..7] wave max, [8..15] wave sum

  if (use_v) {
    const float4* v4 = (const float4*)v;
#pragma unroll
    for (int k = 0; k < 4; ++k) vsh[t + k * 512] = v4[t + k * 512];
  } else {
    const float4 z = make_float4(0.f, 0.f, 0.f, 0.f);
#pragma unroll
    for (int k = 0; k < 4; ++k) vsh[t + k * 512] = z;
  }
  // no barrier: each thread reads back exactly the vsh slots it wrote

  float4 acc[4];
#pragma unroll
  for (int k = 0; k < 4; ++k) acc[k] = make_float4(0.f, 0.f, 0.f, 0.f);

  const float4* s4 = (const float4*)s + (size_t)row0 * NF4 + t;

#pragma unroll 1
  for (int r = 0; r < R; ++r) {
    float4 b[4];
#pragma unroll
    for (int k = 0; k < 4; ++k) b[k] = s4[(size_t)r * NF4 + k * 512];
    // P1: subtract v (in place), wave max
    float m0 = -INFINITY, m1 = -INFINITY, m2 = -INFINITY, m3 = -INFINITY;
#pragma unroll
    for (int k = 0; k < 4; ++k) {
      const float4 vv = vsh[t + k * 512];
      b[k].x -= vv.x; b[k].y -= vv.y; b[k].z -= vv.z; b[k].w -= vv.w;
      m0 = fmaxf(m0, b[k].x); m1 = fmaxf(m1, b[k].y);
      m2 = fmaxf(m2, b[k].z); m3 = fmaxf(m3, b[k].w);
    }
    const float m = wave_max(fmaxf(fmaxf(m0, m1), fmaxf(m2, m3)));
    if (lane == 0) red[wid] = m;
    __syncthreads();
    float bm = red[0];
#pragma unroll
    for (int w = 1; w < 8; ++w) bm = fmaxf(bm, red[w]);
    // P2: exp in place, wave sum
    float s0 = 0.f, s1 = 0.f, s2 = 0.f, s3 = 0.f;
#pragma unroll
    for (int k = 0; k < 4; ++k) {
      b[k].x = __expf(b[k].x - bm); b[k].y = __expf(b[k].y - bm);
      b[k].z = __expf(b[k].z - bm); b[k].w = __expf(b[k].w - bm);
      s0 += b[k].x; s1 += b[k].y; s2 += b[k].z; s3 += b[k].w;
    }
    const float ss = wave_sum((s0 + s1) + (s2 + s3));
    if (lane == 0) red[8 + wid] = ss;
    __syncthreads();
    float tot = red[8];
#pragma unroll
    for (int w = 1; w < 8; ++w) tot += red[8 + w];
    if (t == 0) u[row0 + r] = bm + __logf(tot);
    const float inv = 1.0f / tot;
    // P3: accumulate column partials
#pragma unroll
    for (int k = 0; k < 4; ++k) {
      acc[k].x = fmaf(b[k].x, inv, acc[k].x);
      acc[k].y = fmaf(b[k].y, inv, acc[k].y);
      acc[k].z = fmaf(b[k].z, inv, acc[k].z);
      acc[k].w = fmaf(b[k].w, inv, acc[k].w);
    }
  }

  float4* p4 = (float4*)(pt + (size_t)blockIdx.x * N);
#pragma unroll
  for (int k = 0; k < 4; ++k) p4[t + k * 512] = acc[k];
}

// Stage 1: group-sum strips. ps[g][j] = sum over per_group strips of pt.
__global__ __launch_bounds__(256) void combine1(const float* __restrict__ pt,
                                                float* __restrict__ ps,
                                                int per_group) {
  const int j = blockIdx.x * 256 + threadIdx.x;
  const int g = blockIdx.y;
  const float* p = pt + (size_t)g * per_group * N + j;
  float acc = 0.f;
  for (int c = 0; c < per_group; ++c) acc += p[(size_t)c * N];
  ps[(size_t)g * N + j] = acc;
}

// Stage 2: v'_j = (add_old ? v_j : 0) + log(sum_g ps[g][j])
__global__ __launch_bounds__(256) void combine2(const float* __restrict__ ps,
                                                float* __restrict__ v,
                                                int ngroups, int add_old) {
  const int j = blockIdx.x * 256 + threadIdx.x;
  float T = 0.f;
  for (int g = 0; g < ngroups; ++g) T += ps[(size_t)g * N + j];
  const float lv = __logf(T);
  v[j] = add_old ? v[j] + lv : lv;
}

// out = exp(s - u_i - v_j)
__global__ __launch_bounds__(256) void finalize_k(const float* __restrict__ s,
                                                  const float* __restrict__ u,
                                                  const float* __restrict__ v,
                                                  float* __restrict__ out) {
  const size_t idx = (size_t)blockIdx.x * 256 + threadIdx.x;  // float4 index
  const int row = (int)(idx >> 11);
  const int c4 = (int)(idx & 2047);
  const float4 sv = ((const float4*)s)[idx];
  const float4 vv = ((const float4*)v)[c4];
  const float ur = u[row];
  float4 o;
  o.x = __expf(sv.x - ur - vv.x);
  o.y = __expf(sv.y - ur - vv.y);
  o.z = __expf(sv.z - ur - vv.z);
  o.w = __expf(sv.w - ur - vv.w);
  ((float4*)out)[idx] = o;
}

extern "C" void kernel_launch(void* const* d_in, const int* in_sizes, int n_in,
                              void* d_out, int out_size, void* d_ws, size_t ws_size,
                              hipStream_t stream) {
  const float* s = (const float*)d_in[0];
  float* out = (float*)d_out;
  float* ws = (float*)d_ws;

  // workspace: u[N] | v[N] | ps[8*N] | pt[nstrips*N]
  const size_t avail = ws_size / sizeof(float);
  int nstrips = 512;
  while (nstrips > 128 && (size_t)(10 + nstrips) * N > avail) nstrips >>= 1;
  float* u = ws;
  float* v = ws + N;
  float* ps = ws + 2 * N;
  float* pt = ws + 10 * N;
  const int G = 8;
  const int per_group = nstrips / G;

  for (int p = 0; p < 5; ++p) {
    const int use_v = p > 0 ? 1 : 0;
    switch (nstrips) {
      case 512:
        fused_pass<16><<<512, 512, 0, stream>>>(s, v, u, pt, use_v);
        break;
      case 256:
        fused_pass<32><<<256, 512, 0, stream>>>(s, v, u, pt, use_v);
        break;
      default:
        fused_pass<64><<<128, 512, 0, stream>>>(s, v, u, pt, use_v);
        break;
    }
    combine1<<<dim3(N / 256, G), 256, 0, stream>>>(pt, ps, per_group);
    combine2<<<N / 256, 256, 0, stream>>>(ps, v, G, p > 0 ? 1 : 0);
  }
  finalize_k<<<(N / 256) * NF4, 256, 0, stream>>>(s, u, v, out);
}